// Round 7
// baseline (1259.583 us; speedup 1.0000x reference)
//
#include <hip/hip_runtime.h>
#include <math.h>

#define CH 64
#define HH 128
#define WW 128
#define HW 16384
#define NVALS 131072.f

// ws layout (floats):
//  weff2: ((g*64+c)*9+k)*27 + j   62208 floats
//  bias2: g*27 + j                  108 floats
//  wT:    g*36864 + c*576 + k*64+o 147456 floats
//  stats: sum[64] sumsq[64] a[64] b[64]  256 floats
//  oacc:  ((b*4+g)*27+j)*16384+px  3538944 floats
#define WEFF2 0
#define BIAS2 62208
#define WTOFF 62464
#define STATS 209920
#define OACC  210176

__device__ __forceinline__ int off_chan(int g, int j) {
    return (j < 18) ? (g * 18 + j) : (72 + g * 9 + (j - 18));
}

__global__ void prep(const float* __restrict__ w_offset, const float* __restrict__ b_offset,
                     const float* __restrict__ w_dcn, float* __restrict__ ws) {
    int tid = blockIdx.x * 256 + threadIdx.x;
    if (tid < 147456) {
        int o = tid & 63;
        int k = (tid >> 6) % 9;
        int c = (tid / 576) & 63;
        int g = tid / 36864;
        ws[WTOFF + tid] = w_dcn[((g * 64 + o) * 64 + c) * 9 + k];
    }
    if (tid < 62208) {
        int j = tid % 27;
        int r = tid / 27;
        int k = r % 9;
        int gc = r / 9;
        int c = gc & 63;
        int g = gc >> 6;
        int o = off_chan(g, j);
        float s = 0.f;
#pragma unroll
        for (int ss = 0; ss < 4; ++ss)
            s += w_offset[(o * 256 + ss * 64 + c) * 9 + k];
        ws[WEFF2 + tid] = s;
    }
    if (tid < 108) {
        int g = tid / 27, j = tid % 27;
        ws[BIAS2 + tid] = b_offset[off_chan(g, j)];
    }
    if (tid < 128) ws[STATS + tid] = 0.f;
}

// offset conv, j-chunked by template.  flat grid 512: XCD-pinned batch.
// xcd = blk&7, b = xcd&1, xh = xcd>>1 (0..3), i = blk>>3 (0..63)
// unit = xh*64+i in [0,256): g = unit>>6, tile = unit&63
template <int JBASE, int JN>
__global__ __launch_bounds__(256, 4) void conv_off(const float* __restrict__ x,
                                                   float* __restrict__ ws) {
    int blk = blockIdx.x;
    int xcd = blk & 7;
    int b = xcd & 1;
    int unit = (xcd >> 1) * 64 + (blk >> 3);
    int g = unit >> 6;
    int tile = unit & 63;
    int t = threadIdx.x;
    int h = (tile >> 3) * 16 + (t >> 4);
    int w = (tile & 7) * 16 + (t & 15);
    const float* xb = x + b * CH * HW;

    float oacc[JN];
    const float* bp = ws + BIAS2 + g * 27 + JBASE;
#pragma unroll
    for (int j = 0; j < JN; ++j) oacc[j] = bp[j];

    int offs[9];
    float vmask[9];
#pragma unroll
    for (int k = 0; k < 9; ++k) {
        int yy = h + k / 3 - 1, xx = w + k % 3 - 1;
        bool v = (yy >= 0) && (yy < HH) && (xx >= 0) && (xx < WW);
        vmask[k] = v ? 1.f : 0.f;
        offs[k] = min(max(yy, 0), HH - 1) * WW + min(max(xx, 0), WW - 1);
    }

    const float* wp0 = ws + WEFF2 + (g * 64) * 243 + JBASE;
    for (int c0 = 0; c0 < CH; c0 += 2) {   // c-pairs: 18 gathers in flight
        float xr[2][9];
#pragma unroll
        for (int cc = 0; cc < 2; ++cc) {
            const float* xp = xb + (c0 + cc) * HW;
#pragma unroll
            for (int k = 0; k < 9; ++k) xr[cc][k] = xp[offs[k]];
        }
#pragma unroll
        for (int cc = 0; cc < 2; ++cc) {
            const float* wp = wp0 + (c0 + cc) * 243;
#pragma unroll
            for (int k = 0; k < 9; ++k) {
                float xv = xr[cc][k] * vmask[k];
#pragma unroll
                for (int j = 0; j < JN; ++j)
                    oacc[j] = fmaf(xv, wp[k * 27 + j], oacc[j]);
            }
        }
    }

    float* op = ws + OACC + (size_t)((b * 4 + g) * 27 + JBASE) * HW + h * WW + w;
#pragma unroll
    for (int j = 0; j < JN; ++j) op[(size_t)j * HW] = oacc[j];
}

// deformable conv, o-chunked (32/block).  flat grid 1024: XCD-pinned batch.
// xcd = blk&7, b = xcd&1, xh = xcd>>1, i = blk>>3 (0..127)
// unit = xh*128+i in [0,512): tile = unit&63, go = unit>>6 (0..7): g = go&3, ohalf = go>>2
__global__ __launch_bounds__(256, 4) void dcn(const float* __restrict__ x,
                                              const float* __restrict__ ws,
                                              float* __restrict__ out,
                                              float* __restrict__ stats) {
    int blk = blockIdx.x;
    int xcd = blk & 7;
    int b = xcd & 1;
    int unit = (xcd >> 1) * 128 + (blk >> 3);
    int tile = unit & 63;
    int go = unit >> 6;
    int g = go & 3;
    int obase = (go >> 2) * 32;
    int t = threadIdx.x;
    int h = (tile >> 3) * 16 + (t >> 4);
    int w = (tile & 7) * 16 + (t & 15);
    int px = h * WW + w;
    const float* xb = x + b * CH * HW;
    const float* ob_in = ws + OACC + (size_t)(b * 4 + g) * 27 * HW + px;

    float acc[32];
#pragma unroll
    for (int o = 0; o < 32; ++o) acc[o] = 0.f;

    const float* wg = ws + WTOFF + g * 36864 + obase;
#pragma unroll
    for (int k = 0; k < 9; ++k) {
        float dy = ob_in[(size_t)(2 * k) * HW];
        float dx = ob_in[(size_t)(2 * k + 1) * HW];
        float mk = 1.f / (1.f + expf(-ob_in[(size_t)(18 + k) * HW]));

        float py = (float)h + (float)(k / 3 - 1) + dy;
        float qx = (float)w + (float)(k % 3 - 1) + dx;
        float y0f = floorf(py), x0f = floorf(qx);
        float ly = py - y0f, lx = qx - x0f;
        int y0 = (int)y0f, x0 = (int)x0f;
        int y1 = y0 + 1, x1 = x0 + 1;

        bool vy0 = (y0 >= 0) && (y0 < HH), vy1 = (y1 >= 0) && (y1 < HH);
        bool vx0 = (x0 >= 0) && (x0 < WW), vx1 = (x1 >= 0) && (x1 < WW);
        int yc0 = min(max(y0, 0), HH - 1), yc1 = min(max(y1, 0), HH - 1);
        int xc0 = min(max(x0, 0), WW - 1), xc1 = min(max(x1, 0), WW - 1);
        int i00 = yc0 * WW + xc0, i01 = yc0 * WW + xc1;
        int i10 = yc1 * WW + xc0, i11 = yc1 * WW + xc1;

        float w00 = (1.f - ly) * (1.f - lx) * mk * ((vy0 && vx0) ? 1.f : 0.f);
        float w01 = (1.f - ly) * lx * mk * ((vy0 && vx1) ? 1.f : 0.f);
        float w10 = ly * (1.f - lx) * mk * ((vy1 && vx0) ? 1.f : 0.f);
        float w11 = ly * lx * mk * ((vy1 && vx1) ? 1.f : 0.f);

        const float* wk = wg + k * 64;
        for (int c0 = 0; c0 < CH; c0 += 4) {   // c-quads: 16 gathers in flight
            float xv[4][4];
#pragma unroll
            for (int cc = 0; cc < 4; ++cc) {
                const float* xp = xb + (c0 + cc) * HW;
                xv[cc][0] = xp[i00];
                xv[cc][1] = xp[i01];
                xv[cc][2] = xp[i10];
                xv[cc][3] = xp[i11];
            }
#pragma unroll
            for (int cc = 0; cc < 4; ++cc) {
                float col = w00 * xv[cc][0] + w01 * xv[cc][1]
                          + w10 * xv[cc][2] + w11 * xv[cc][3];
                const float* wp = wk + (c0 + cc) * 576;   // wave-uniform -> scalar loads
#pragma unroll
                for (int o = 0; o < 32; ++o)
                    acc[o] = fmaf(col, wp[o], acc[o]);
            }
        }
    }

    int h2 = h * 2 + (g >> 1), w2 = w * 2 + (g & 1);
    float* op = out + (size_t)b * 64 * 65536 + (size_t)obase * 65536
              + (size_t)h2 * 256 + w2;
#pragma unroll
    for (int o = 0; o < 32; ++o)
        op[(size_t)o * 65536] = acc[o];

#pragma unroll
    for (int o = 0; o < 32; ++o) {
        float v = acc[o];
        float v2 = v * v;
#pragma unroll
        for (int m = 32; m >= 1; m >>= 1) {
            v += __shfl_xor(v, m);
            v2 += __shfl_xor(v2, m);
        }
        if ((t & 63) == 0) {
            atomicAdd(stats + obase + o, v);
            atomicAdd(stats + 64 + obase + o, v2);
        }
    }
}

__global__ void finalize(const float* __restrict__ stats,
                         const float* __restrict__ gamma,
                         const float* __restrict__ beta,
                         float* __restrict__ ab) {
    int t = threadIdx.x;
    if (t < 64) {
        float mean = stats[t] / NVALS;
        float var = stats[64 + t] / NVALS - mean * mean;
        var = fmaxf(var, 0.f);
        float a = gamma[t] * rsqrtf(var + 1e-5f);
        ab[t] = a;
        ab[64 + t] = beta[t] - mean * a;
    }
}

__global__ void norm_relu(float* __restrict__ out, const float* __restrict__ ab) {
    size_t tid = (size_t)blockIdx.x * 256 + threadIdx.x;
    size_t base = tid * 4;
    int o = (int)((base >> 16) & 63);
    float a = ab[o], bb = ab[64 + o];
    float4* p = (float4*)(out + base);
    float4 v = *p;
    v.x = fmaxf(fmaf(v.x, a, bb), 0.f);
    v.y = fmaxf(fmaf(v.y, a, bb), 0.f);
    v.z = fmaxf(fmaf(v.z, a, bb), 0.f);
    v.w = fmaxf(fmaf(v.w, a, bb), 0.f);
    *p = v;
}

extern "C" void kernel_launch(void* const* d_in, const int* in_sizes, int n_in,
                              void* d_out, int out_size, void* d_ws, size_t ws_size,
                              hipStream_t stream) {
    const float* x        = (const float*)d_in[0];
    const float* w_offset = (const float*)d_in[1];
    const float* b_offset = (const float*)d_in[2];
    const float* w_dcn    = (const float*)d_in[3];
    const float* gamma    = (const float*)d_in[4];
    const float* beta     = (const float*)d_in[5];
    float* out            = (float*)d_out;
    float* ws = (float*)d_ws;

    prep<<<576, 256, 0, stream>>>(w_offset, b_offset, w_dcn, ws);
    conv_off<0, 14><<<512, 256, 0, stream>>>(x, ws);
    conv_off<14, 13><<<512, 256, 0, stream>>>(x, ws);
    dcn<<<1024, 256, 0, stream>>>(x, ws, out, ws + STATS);
    finalize<<<1, 64, 0, stream>>>(ws + STATS, gamma, beta, ws + STATS + 128);
    norm_relu<<<8192, 256, 0, stream>>>(out, ws + STATS + 128);
}